// Round 8
// baseline (162.354 us; speedup 1.0000x reference)
//
#include <hip/hip_runtime.h>
#include <stddef.h>

#define IMG_N 4096

typedef float vf4 __attribute__((ext_vector_type(4)));

// 4 tiles of 64x32 output per block, walked left->right. 256 threads.
// R7 + two fixes:
//  (1) mid-loop waits are COUNTED: s_waitcnt vmcnt(2) — drains the RAW DMA
//      prefetch loads but leaves this tile's 2 NT output stores in flight
//      (R7's vmcnt(0) serialized store-retire latency into every tile).
//  (2) weights/biases staged to LDS in the prologue — the K-loop then has
//      NO vector-global reads, so the compiler can't insert a stray
//      vmcnt drain before weight use.
#define S_HH1   0        // 1056 (24 rows x stride 44, 40 cols used)
#define S_LH1   1056     // 1056
#define S_HL1   2112     // 1056
#define S_LL2   3168     // 240  (12 x 20)
#define S_LH2   3408     // 240
#define S_HL2   3648     // 240
#define S_HH2   3888     // 240
#define S_HH1C  4128     // 576  (16 x stride 36, 32 used)
#define S_HH2C  4704     // 160  (8 x 20, 16 used)
#define S_LL3   4864     // 60   (6 x 10)
#define S_LH3   4924
#define S_HL3   4984
#define S_HH3   5044
#define S_RAW   5104     // 3840 (48 rows x 80 cols, raw halo staging)
#define S_W     8944     // 96: w7[49] w5[25] w3[9] pad | b7 b5 b3 @ 83,84,85
#define S_TOTAL 9040
#define S_LL1P  S_HH1    // 576 (16 x stride 36), written P3, read P4

// Raw barrier: LDS visibility only; async loads + NT stores stay outstanding.
#define BAR() do { asm volatile("s_waitcnt lgkmcnt(0)" ::: "memory"); \
                   __builtin_amdgcn_s_barrier(); } while (0)
// Counted wait: RAW DMA loads (older) done; <=2 newest vmem (NT stores) live.
#define WAIT_LOADS_BAR() do { \
    asm volatile("s_waitcnt vmcnt(2) lgkmcnt(0)" ::: "memory"); \
    __builtin_amdgcn_s_barrier(); } while (0)
// Full drain (prologue only; no stores outstanding yet).
#define VM_DRAIN_BAR() do { \
    asm volatile("s_waitcnt vmcnt(0) lgkmcnt(0)" ::: "memory"); \
    __builtin_amdgcn_s_barrier(); } while (0)

__device__ __forceinline__ void gl_lds16(const float* gp, float* lp) {
    __builtin_amdgcn_global_load_lds(
        (const __attribute__((address_space(1))) void*)gp,
        (__attribute__((address_space(3))) void*)lp, 16, 0, 0);
}

// ---- async: stream 48x80 raw halo of tile at C0T into RAW (linear fill).
//      15 issues of 1024 B; wave wv takes issues wv, wv+4, wv+8, wv+12. ----
#define ISSUE_ASYNC(C0T)                                                       \
  do {                                                                         \
    const int c0a_ = (C0T);                                                    \
    _Pragma("unroll")                                                          \
    for (int k_ = 0; k_ < 4; ++k_) {                                           \
      const int i_ = wv + 4 * k_;                                              \
      if (i_ < 15) {                                                           \
        const int of_ = i_ * 256 + lane * 4;                                   \
        const int row_ = of_ / 80;                                             \
        const int col_ = of_ - row_ * 80;                                      \
        gl_lds16(x + (size_t)(R0 - 8 + row_) * IMG_N + (c0a_ - 8) + col_,      \
                 RAW + i_ * 256);                                              \
      }                                                                        \
    }                                                                          \
  } while (0)

// ---- synchronous zero-padded fill for border tiles (15 floats/thread) ----
#define SYNC_FILL(C0T)                                                         \
  do {                                                                         \
    const int c0f_ = (C0T);                                                    \
    _Pragma("unroll")                                                          \
    for (int k_ = 0; k_ < 15; ++k_) {                                          \
      const int idx_ = tid + 256 * k_;                                         \
      const int row_ = idx_ / 80, col_ = idx_ - row_ * 80;                     \
      const int gr_ = R0 - 8 + row_, gc_ = c0f_ - 8 + col_;                    \
      const bool v_ = (gr_ >= 0 && gr_ < IMG_N && gc_ >= 0 && gc_ < IMG_N);    \
      RAW[idx_] = v_ ? x[(size_t)gr_ * IMG_N + gc_] : 0.0f;                    \
    }                                                                          \
  } while (0)

// ---- DWT1 (RAW LDS -> subband LDS) + DWT2 (lane+10 shfl -> LDS) ----
#define CONSUME_RAW()                                                          \
  do {                                                                         \
    if (loader) {                                                              \
      const float* rp_ = RAW + (2 * mrow) * 80 + 8 * g;                        \
      const float4 t0 = *(const float4*)(rp_);                                 \
      const float4 t1 = *(const float4*)(rp_ + 4);                             \
      const float4 c0 = *(const float4*)(rp_ + 80);                            \
      const float4 c1 = *(const float4*)(rp_ + 84);                            \
      float ll0_, ll1_, ll2_, ll3_;                                            \
      float4 lhv_, hlv_, hhv_;                                                 \
      {                                                                        \
        float a = t0.x, b = t0.y, c = c0.x, d = c0.y;                          \
        ll0_ = (a+b+c+d)*0.5f; lhv_.x = (a+b-c-d)*0.5f;                        \
        hlv_.x = (a-b+c-d)*0.5f; hhv_.x = (a-b-c+d)*0.5f;                      \
        a = t0.z; b = t0.w; c = c0.z; d = c0.w;                                \
        ll1_ = (a+b+c+d)*0.5f; lhv_.y = (a+b-c-d)*0.5f;                        \
        hlv_.y = (a-b+c-d)*0.5f; hhv_.y = (a-b-c+d)*0.5f;                      \
        a = t1.x; b = t1.y; c = c1.x; d = c1.y;                                \
        ll2_ = (a+b+c+d)*0.5f; lhv_.z = (a+b-c-d)*0.5f;                        \
        hlv_.z = (a-b+c-d)*0.5f; hhv_.z = (a-b-c+d)*0.5f;                      \
        a = t1.z; b = t1.w; c = c1.z; d = c1.w;                                \
        ll3_ = (a+b+c+d)*0.5f; lhv_.w = (a+b-c-d)*0.5f;                        \
        hlv_.w = (a-b+c-d)*0.5f; hhv_.w = (a-b-c+d)*0.5f;                      \
      }                                                                        \
      const int o_ = mrow * 44 + 4 * g;                                        \
      *(float4*)(LH1 + o_) = lhv_;                                             \
      *(float4*)(HL1 + o_) = hlv_;                                             \
      *(float4*)(HH1 + o_) = hhv_;                                             \
      const float pb0_ = __shfl(ll0_, lane + 10, 64);                          \
      const float pb1_ = __shfl(ll1_, lane + 10, 64);                          \
      const float pb2_ = __shfl(ll2_, lane + 10, 64);                          \
      const float pb3_ = __shfl(ll3_, lane + 10, 64);                          \
      if (mtop) {                                                              \
        const int q_ = mrow >> 1;                                              \
        float2 l2ll_, l2lh_, l2hl_, l2hh_;                                     \
        float a = ll0_, b = ll1_, c = pb0_, d = pb1_;                          \
        l2ll_.x = (a+b+c+d)*0.5f; l2lh_.x = (a+b-c-d)*0.5f;                    \
        l2hl_.x = (a-b+c-d)*0.5f; l2hh_.x = (a-b-c+d)*0.5f;                    \
        a = ll2_; b = ll3_; c = pb2_; d = pb3_;                                \
        l2ll_.y = (a+b+c+d)*0.5f; l2lh_.y = (a+b-c-d)*0.5f;                    \
        l2hl_.y = (a-b+c-d)*0.5f; l2hh_.y = (a-b-c+d)*0.5f;                    \
        const int o2_ = q_ * 20 + 2 * g;                                       \
        *(float2*)(LL2 + o2_) = l2ll_; *(float2*)(LH2 + o2_) = l2lh_;          \
        *(float2*)(HL2 + o2_) = l2hl_; *(float2*)(HH2 + o2_) = l2hh_;          \
      }                                                                        \
    }                                                                          \
  } while (0)

// ---- P2+P3+P4 for the tile whose data is in LDS; C0T = output col base.
//      Weights read from LDS (WL) — no global vmem in here. ----
#define COMPUTE_STORE(C0T)                                                     \
  do {                                                                         \
    const int c0s_ = (C0T);                                                    \
    /* P2: conv7 (0-127) || conv5 (128-159) || DWT3 (160-189) */               \
    if (tid < 128) {                                                           \
      const int i_ = tid >> 3;                                                 \
      const int j0_ = (tid & 7) << 2;                                          \
      const float bias_ = WL[83];                                              \
      float a0_ = bias_, a1_ = bias_, a2_ = bias_, a3_ = bias_;                \
      _Pragma("unroll")                                                        \
      for (int dy_ = 0; dy_ < 7; ++dy_) {                                      \
        const float* rp_ = HH1 + (i_ + dy_ + 1) * 44 + j0_;                    \
        float4 A_ = *(const float4*)(rp_);                                     \
        float4 B_ = *(const float4*)(rp_ + 4);                                 \
        float4 C_ = *(const float4*)(rp_ + 8);                                 \
        const float* wr_ = WL + dy_ * 7;                                       \
        float q0_ = wr_[0], q1_ = wr_[1], q2_ = wr_[2], q3_ = wr_[3],          \
              q4_ = wr_[4], q5_ = wr_[5], q6_ = wr_[6];                        \
        a0_ += q0_*A_.y + q1_*A_.z + q2_*A_.w + q3_*B_.x + q4_*B_.y            \
             + q5_*B_.z + q6_*B_.w;                                            \
        a1_ += q0_*A_.z + q1_*A_.w + q2_*B_.x + q3_*B_.y + q4_*B_.z            \
             + q5_*B_.w + q6_*C_.x;                                            \
        a2_ += q0_*A_.w + q1_*B_.x + q2_*B_.y + q3_*B_.z + q4_*B_.w            \
             + q5_*C_.x + q6_*C_.y;                                            \
        a3_ += q0_*B_.x + q1_*B_.y + q2_*B_.z + q3_*B_.w + q4_*C_.x            \
             + q5_*C_.y + q6_*C_.z;                                            \
      }                                                                        \
      *(float4*)(HH1C + i_ * 36 + j0_) = make_float4(a0_, a1_, a2_, a3_);      \
    } else if (tid < 160) {                                                    \
      const int s_ = tid - 128;                                                \
      const int i_ = s_ >> 2;                                                  \
      const int j0_ = (s_ & 3) << 2;                                           \
      const float bias_ = WL[84];                                              \
      float a0_ = bias_, a1_ = bias_, a2_ = bias_, a3_ = bias_;                \
      _Pragma("unroll")                                                        \
      for (int dy_ = 0; dy_ < 5; ++dy_) {                                      \
        const float* rp_ = HH2 + (i_ + dy_) * 20 + j0_;                        \
        float4 A_ = *(const float4*)(rp_);                                     \
        float4 B_ = *(const float4*)(rp_ + 4);                                 \
        const float* wr_ = WL + 49 + dy_ * 5;                                  \
        float q0_ = wr_[0], q1_ = wr_[1], q2_ = wr_[2], q3_ = wr_[3],          \
              q4_ = wr_[4];                                                    \
        a0_ += q0_*A_.x + q1_*A_.y + q2_*A_.z + q3_*A_.w + q4_*B_.x;           \
        a1_ += q0_*A_.y + q1_*A_.z + q2_*A_.w + q3_*B_.x + q4_*B_.y;           \
        a2_ += q0_*A_.z + q1_*A_.w + q2_*B_.x + q3_*B_.y + q4_*B_.z;           \
        a3_ += q0_*A_.w + q1_*B_.x + q2_*B_.y + q3_*B_.z + q4_*B_.w;           \
      }                                                                        \
      *(float4*)(HH2C + i_ * 20 + j0_) = make_float4(a0_, a1_, a2_, a3_);      \
    } else if (tid < 190) {                                                    \
      const int tt_ = tid - 160;                                               \
      const int u_ = tt_ / 5, v2_ = (tt_ % 5) * 2;                             \
      const float* rp_ = LL2 + (2 * u_) * 20 + 2 * v2_;                        \
      float4 t0_ = *(const float4*)(rp_);                                      \
      float4 c0_ = *(const float4*)(rp_ + 20);                                 \
      const int o_ = u_ * 10 + v2_;                                            \
      *(float2*)(LL3 + o_) = make_float2((t0_.x + t0_.y + c0_.x + c0_.y) * 0.5f, \
                                         (t0_.z + t0_.w + c0_.z + c0_.w) * 0.5f); \
      *(float2*)(LH3 + o_) = make_float2((t0_.x + t0_.y - c0_.x - c0_.y) * 0.5f, \
                                         (t0_.z + t0_.w - c0_.z - c0_.w) * 0.5f); \
      *(float2*)(HL3 + o_) = make_float2((t0_.x - t0_.y + c0_.x - c0_.y) * 0.5f, \
                                         (t0_.z - t0_.w + c0_.z - c0_.w) * 0.5f); \
      *(float2*)(HH3 + o_) = make_float2((t0_.x - t0_.y - c0_.x + c0_.y) * 0.5f, \
                                         (t0_.z - t0_.w - c0_.z + c0_.w) * 0.5f); \
    }                                                                          \
    BAR(); /* B2 */                                                            \
    /* P3: conv3 + IDWT3 + IDWT2 fused (tid 0-63) */                           \
    if (tid < 64) {                                                            \
      const int p_ = tid >> 3, c_ = tid & 7;                                   \
      const int r_ = p_ >> 1;                                                  \
      const float sr_ = (p_ & 1) ? -1.0f : 1.0f;                               \
      float hh_ = WL[85];                                                      \
      _Pragma("unroll")                                                        \
      for (int dy_ = 0; dy_ < 3; ++dy_) {                                      \
        const float* row_ = HH3 + (r_ + dy_) * 10 + c_;                        \
        const float* wr_ = WL + 74 + dy_ * 3;                                  \
        hh_ += wr_[0]*row_[0] + wr_[1]*row_[1] + wr_[2]*row_[2];               \
      }                                                                        \
      const int li3_ = (r_ + 1) * 10 + (c_ + 1);                               \
      const float lo3_ = LL3[li3_] + sr_ * LH3[li3_];                          \
      const float hi3_ = HL3[li3_] + sr_ * hh_;                                \
      const float v0_ = (lo3_ + hi3_) * 0.5f;                                  \
      const float v1_ = (lo3_ - hi3_) * 0.5f;                                  \
      const int li2_ = (p_ + 2) * 20 + (2 * c_ + 2);                           \
      float2 lh2_ = *(const float2*)(LH2 + li2_);                              \
      float2 hl2_ = *(const float2*)(HL2 + li2_);                              \
      float2 hc_  = *(const float2*)(HH2C + p_ * 20 + 2 * c_);                 \
      _Pragma("unroll")                                                        \
      for (int q_ = 0; q_ < 2; ++q_) {                                         \
        const float s2_ = q_ ? -1.0f : 1.0f;                                   \
        const float lo0_ = v0_ + s2_ * lh2_.x;                                 \
        const float hi0_ = hl2_.x + s2_ * hc_.x;                               \
        const float lo1_ = v1_ + s2_ * lh2_.y;                                 \
        const float hi1_ = hl2_.y + s2_ * hc_.y;                               \
        *(float4*)(LL1P + (2 * p_ + q_) * 36 + 4 * c_) =                       \
            make_float4((lo0_ + hi0_) * 0.5f, (lo0_ - hi0_) * 0.5f,            \
                        (lo1_ + hi1_) * 0.5f, (lo1_ - hi1_) * 0.5f);           \
      }                                                                        \
    }                                                                          \
    BAR(); /* B3 */                                                            \
    /* P4: IDWT1 -> out (64x32), NT float4 stores */                           \
    _Pragma("unroll")                                                          \
    for (int k_ = 0; k_ < 2; ++k_) {                                           \
      const int idx_ = tid + 256 * k_;                                         \
      const int p_ = idx_ >> 4;                                                \
      const int c2_ = (idx_ & 15) * 2;                                         \
      const int r_ = p_ >> 1;                                                  \
      const float sr_ = (p_ & 1) ? -1.0f : 1.0f;                               \
      const int li_ = (r_ + 4) * 44 + (c2_ + 4);                               \
      const int ci_ = r_ * 36 + c2_;                                           \
      float2 llp_ = *(const float2*)(LL1P + ci_);                              \
      float2 lh_  = *(const float2*)(LH1 + li_);                               \
      float2 hl_  = *(const float2*)(HL1 + li_);                               \
      float2 hhc_ = *(const float2*)(HH1C + ci_);                              \
      float lo0_ = llp_.x + sr_ * lh_.x;                                       \
      float hi0_ = hl_.x + sr_ * hhc_.x;                                       \
      float lo1_ = llp_.y + sr_ * lh_.y;                                       \
      float hi1_ = hl_.y + sr_ * hhc_.y;                                       \
      vf4 o_ = { (lo0_ + hi0_) * 0.5f, (lo0_ - hi0_) * 0.5f,                   \
                 (lo1_ + hi1_) * 0.5f, (lo1_ - hi1_) * 0.5f };                 \
      __builtin_nontemporal_store(                                             \
          o_, (vf4*)(out + (size_t)(R0 + p_) * IMG_N + c0s_ + 2 * c2_));       \
    }                                                                          \
  } while (0)

__global__ __launch_bounds__(256, 4) void haar_fused(
    const float* __restrict__ x,
    const float* __restrict__ w3, const float* __restrict__ b3,
    const float* __restrict__ w5, const float* __restrict__ b5,
    const float* __restrict__ w7, const float* __restrict__ b7,
    float* __restrict__ out)
{
    __shared__ __align__(16) float sm[S_TOTAL];
    const int tid = threadIdx.x;
    const int bx = blockIdx.x, by = blockIdx.y;
    const int R0 = by * 32;
    const int C0base = bx * 256;

    float* HH1  = sm + S_HH1;
    float* LH1  = sm + S_LH1;   float* HL1 = sm + S_HL1;
    float* LL2  = sm + S_LL2;   float* LH2 = sm + S_LH2;
    float* HL2  = sm + S_HL2;   float* HH2 = sm + S_HH2;
    float* HH1C = sm + S_HH1C;  float* HH2C = sm + S_HH2C;
    float* LL3  = sm + S_LL3;   float* LH3 = sm + S_LH3;
    float* HL3  = sm + S_HL3;   float* HH3 = sm + S_HH3;
    float* LL1P = sm + S_LL1P;
    float* RAW  = sm + S_RAW;
    float* WL   = sm + S_W;

    // Loader mapping: 240 items = 24 L1-rows x 10 col-groups; 60 lanes/wave.
    const int lane = tid & 63, wv = tid >> 6;
    const bool loader = (lane < 60);
    const int mrow = 6 * wv + lane / 10;    // 0..23
    const int g = lane % 10;                // 0..9
    const bool mtop = (((lane / 10) & 1) == 0);

    // ---- stage weights to LDS (one-time; keeps K-loop free of global vmem) ----
    if (tid < 49)            WL[tid] = w7[tid];
    else if (tid < 74)       WL[tid] = w5[tid - 49];
    else if (tid < 83)       WL[tid] = w3[tid - 74];
    else if (tid == 83)      WL[83] = b7[0];
    else if (tid == 84)      WL[84] = b5[0];
    else if (tid == 85)      WL[85] = b3[0];

    const bool rows_ok = (by >= 1) && (by <= 126);
#define TILE_INTERIOR(C0T) (rows_ok && ((C0T) >= 8) && ((C0T) <= 4024))

    // ---- prologue: stage tile 0's raw halo ----
    {
        const int C00 = C0base;
        if (TILE_INTERIOR(C00)) {
            ISSUE_ASYNC(C00);
            VM_DRAIN_BAR();
        } else {
            SYNC_FILL(C00);
            BAR();
        }
    }

    // ---- tile 0 ----
    CONSUME_RAW();
    BAR();   // B1
    {
        const int C0n = C0base + 64;
        if (TILE_INTERIOR(C0n)) {
            ISSUE_ASYNC(C0n);             // in flight under P2-P4
            COMPUTE_STORE(C0base);
            WAIT_LOADS_BAR();             // loads done; NT stores stay in flight
        } else {
            COMPUTE_STORE(C0base);
            SYNC_FILL(C0n);
            BAR();
        }
    }

    // ---- tile 1 ----
    CONSUME_RAW();
    BAR();
    {
        const int C0n = C0base + 128;
        if (TILE_INTERIOR(C0n)) {
            ISSUE_ASYNC(C0n);
            COMPUTE_STORE(C0base + 64);
            WAIT_LOADS_BAR();
        } else {
            COMPUTE_STORE(C0base + 64);
            SYNC_FILL(C0n);
            BAR();
        }
    }

    // ---- tile 2 ----
    CONSUME_RAW();
    BAR();
    {
        const int C0n = C0base + 192;
        if (TILE_INTERIOR(C0n)) {
            ISSUE_ASYNC(C0n);
            COMPUTE_STORE(C0base + 128);
            WAIT_LOADS_BAR();
        } else {
            COMPUTE_STORE(C0base + 128);
            SYNC_FILL(C0n);
            BAR();
        }
    }

    // ---- tile 3 (no prefetch; stores drain at kernel end) ----
    CONSUME_RAW();
    BAR();
    COMPUTE_STORE(C0base + 192);
}

extern "C" void kernel_launch(void* const* d_in, const int* in_sizes, int n_in,
                              void* d_out, int out_size, void* d_ws, size_t ws_size,
                              hipStream_t stream) {
    (void)in_sizes; (void)n_in; (void)out_size; (void)d_ws; (void)ws_size;
    const float* x  = (const float*)d_in[0];
    const float* w3 = (const float*)d_in[1];
    const float* b3 = (const float*)d_in[2];
    const float* w5 = (const float*)d_in[3];
    const float* b5 = (const float*)d_in[4];
    const float* w7 = (const float*)d_in[5];
    const float* b7 = (const float*)d_in[6];
    float* out = (float*)d_out;

    dim3 grid(IMG_N / 256, IMG_N / 32);    // 16 x 128 blocks, 4 tiles each
    dim3 block(256);
    haar_fused<<<grid, block, 0, stream>>>(x, w3, b3, w5, b5, w7, b7, out);
}

// Round 10
// 137.610 us; speedup vs baseline: 1.1798x; 1.1798x over previous
//
#include <hip/hip_runtime.h>
#include <stddef.h>

#define IMG_N 4096

typedef float vf4 __attribute__((ext_vector_type(4)));

// 64-wide x 32-tall output tiles, 256 threads, 8 blocks/CU.
// R2 (twice-verified, 46.4 us/dispatch) + ONE change: a block-uniform
// start-time stagger (s_sleep prologue, ~960-cycle steps keyed on block id)
// to break the inter-block phase convoy (all 8 co-resident blocks issuing
// loads simultaneously, then all computing -> neither HBM nor VALU >40%).
// LDS layout (float offsets), total 5104 floats = 20,416 B.
// Phase plan (3 barriers):
//   P1: load 80x48 + DWT1 + DWT2   (120 items of 4x8 patch, spread over 4 waves)
//   P2: conv7 (tid 0-127) || conv5 (128-159) || DWT3 (160-189)
//   P3: conv3 + IDWT3 + IDWT2 fused (tid 0-63; LL2P lives in registers)
//   P4: IDWT1 -> out (64x32), NT float4 stores, 2 rounds
// Alias: raw HH1 dead after P2 (conv7) -> slot hosts LL1P (16 x stride 36).
#define S_HH1   0        // 1056 (24 rows x stride 44, 40 used)
#define S_LH1   1056     // 1056
#define S_HL1   2112     // 1056
#define S_LL2   3168     // 240  (12 x 20)
#define S_LH2   3408     // 240
#define S_HL2   3648     // 240
#define S_HH2   3888     // 240
#define S_HH1C  4128     // 576  (16 x stride 36, 32 used)
#define S_HH2C  4704     // 160  (8 x 20, 16 used)
#define S_LL3   4864     // 60   (6 x 10)
#define S_LH3   4924
#define S_HL3   4984
#define S_HH3   5044
#define S_TOTAL 5104
#define S_LL1P  S_HH1    // 576 (16 x stride 36), written P3, read P4

__global__ __launch_bounds__(256, 8) void haar_fused(
    const float* __restrict__ x,
    const float* __restrict__ w3, const float* __restrict__ b3,
    const float* __restrict__ w5, const float* __restrict__ b5,
    const float* __restrict__ w7, const float* __restrict__ b7,
    float* __restrict__ out)
{
    __shared__ __align__(16) float sm[S_TOTAL];
    const int tid = threadIdx.x;
    const int bx = blockIdx.x, by = blockIdx.y;
    const int R0 = by * 32, C0 = bx * 64;

    // ---- start-time stagger: desync co-resident blocks' phase bursts.
    // Block-uniform; ~960 cycles per step, 0..7 steps. Works for both
    // chunked and round-robin block->CU assignment via bid ^ (bid>>8).
    {
        const int bid = by * 64 + bx;           // gridDim.x == 64
        const int stag = (bid ^ (bid >> 8)) & 7;
        #pragma unroll 1
        for (int i = 0; i < stag; ++i) __builtin_amdgcn_s_sleep(15);
    }

    float* HH1  = sm + S_HH1;
    float* LH1  = sm + S_LH1;   float* HL1 = sm + S_HL1;
    float* LL2  = sm + S_LL2;   float* LH2 = sm + S_LH2;
    float* HL2  = sm + S_HL2;   float* HH2 = sm + S_HH2;
    float* HH1C = sm + S_HH1C;  float* HH2C = sm + S_HH2C;
    float* LL3  = sm + S_LL3;   float* LH3 = sm + S_LH3;
    float* HL3  = sm + S_HL3;   float* HH3 = sm + S_HH3;
    float* LL1P = sm + S_LL1P;

    // ==== P1: global load + DWT1 + DWT2. 120 items = 12 row-groups x 10 col-groups.
    // Spread 30 items per wave (4 waves) for more VMEM issue streams.
    // Each item: 4x8 pixel patch (8 dwordx4 loads) -> 2 rows x 4 cols of L1 coeffs
    // (LH/HL/HH to LDS, LL kept in registers) -> 1 row x 2 cols of L2 coeffs to LDS.
    const bool interior = (by >= 1) && (by <= 126) && (bx >= 1) && (bx <= 62);
    const int lane = tid & 63, wv = tid >> 6;
    if (lane < 30) {
        const int item = wv * 30 + lane;
        const int u = item / 10, g = item % 10;
        float v[4][8];
        if (interior) {
            const float* p = x + (size_t)(R0 - 8 + 4 * u) * IMG_N + (C0 - 8 + 8 * g);
            #pragma unroll
            for (int k = 0; k < 4; ++k) {
                float4 a = *(const float4*)(p + (size_t)k * IMG_N);
                float4 b = *(const float4*)(p + (size_t)k * IMG_N + 4);
                v[k][0] = a.x; v[k][1] = a.y; v[k][2] = a.z; v[k][3] = a.w;
                v[k][4] = b.x; v[k][5] = b.y; v[k][6] = b.z; v[k][7] = b.w;
            }
        } else {
            const int gr = R0 - 8 + 4 * u, gc = C0 - 8 + 8 * g;
            #pragma unroll
            for (int k = 0; k < 4; ++k) {
                const int grk = gr + k;
                const bool rv = (grk >= 0 && grk < IMG_N);
                #pragma unroll
                for (int j = 0; j < 8; ++j) {
                    const int gcj = gc + j;
                    v[k][j] = (rv && gcj >= 0 && gcj < IMG_N)
                              ? x[(size_t)grk * IMG_N + gcj] : 0.0f;
                }
            }
        }
        float ll0[4], ll1[4];
        // row-pair 0: input rows 0,1 -> L1 row 2u
        {
            float4 lhv, hlv, hhv;
            float a = v[0][0], b = v[0][1], c = v[1][0], d = v[1][1];
            ll0[0] = (a+b+c+d)*0.5f; lhv.x = (a+b-c-d)*0.5f;
            hlv.x = (a-b+c-d)*0.5f;  hhv.x = (a-b-c+d)*0.5f;
            a = v[0][2]; b = v[0][3]; c = v[1][2]; d = v[1][3];
            ll0[1] = (a+b+c+d)*0.5f; lhv.y = (a+b-c-d)*0.5f;
            hlv.y = (a-b+c-d)*0.5f;  hhv.y = (a-b-c+d)*0.5f;
            a = v[0][4]; b = v[0][5]; c = v[1][4]; d = v[1][5];
            ll0[2] = (a+b+c+d)*0.5f; lhv.z = (a+b-c-d)*0.5f;
            hlv.z = (a-b+c-d)*0.5f;  hhv.z = (a-b-c+d)*0.5f;
            a = v[0][6]; b = v[0][7]; c = v[1][6]; d = v[1][7];
            ll0[3] = (a+b+c+d)*0.5f; lhv.w = (a+b-c-d)*0.5f;
            hlv.w = (a-b+c-d)*0.5f;  hhv.w = (a-b-c+d)*0.5f;
            const int o = (2 * u) * 44 + 4 * g;
            *(float4*)(LH1 + o) = lhv; *(float4*)(HL1 + o) = hlv;
            *(float4*)(HH1 + o) = hhv;
        }
        // row-pair 1: input rows 2,3 -> L1 row 2u+1
        {
            float4 lhv, hlv, hhv;
            float a = v[2][0], b = v[2][1], c = v[3][0], d = v[3][1];
            ll1[0] = (a+b+c+d)*0.5f; lhv.x = (a+b-c-d)*0.5f;
            hlv.x = (a-b+c-d)*0.5f;  hhv.x = (a-b-c+d)*0.5f;
            a = v[2][2]; b = v[2][3]; c = v[3][2]; d = v[3][3];
            ll1[1] = (a+b+c+d)*0.5f; lhv.y = (a+b-c-d)*0.5f;
            hlv.y = (a-b+c-d)*0.5f;  hhv.y = (a-b-c+d)*0.5f;
            a = v[2][4]; b = v[2][5]; c = v[3][4]; d = v[3][5];
            ll1[2] = (a+b+c+d)*0.5f; lhv.z = (a+b-c-d)*0.5f;
            hlv.z = (a-b+c-d)*0.5f;  hhv.z = (a-b-c+d)*0.5f;
            a = v[2][6]; b = v[2][7]; c = v[3][6]; d = v[3][7];
            ll1[3] = (a+b+c+d)*0.5f; lhv.w = (a+b-c-d)*0.5f;
            hlv.w = (a-b+c-d)*0.5f;  hhv.w = (a-b-c+d)*0.5f;
            const int o = (2 * u + 1) * 44 + 4 * g;
            *(float4*)(LH1 + o) = lhv; *(float4*)(HL1 + o) = hlv;
            *(float4*)(HH1 + o) = hhv;
        }
        // DWT2 on the in-register 2x4 LL block -> L2 row u, cols 2g..2g+1
        {
            float2 l2ll, l2lh, l2hl, l2hh;
            float a = ll0[0], b = ll0[1], c = ll1[0], d = ll1[1];
            l2ll.x = (a+b+c+d)*0.5f; l2lh.x = (a+b-c-d)*0.5f;
            l2hl.x = (a-b+c-d)*0.5f; l2hh.x = (a-b-c+d)*0.5f;
            a = ll0[2]; b = ll0[3]; c = ll1[2]; d = ll1[3];
            l2ll.y = (a+b+c+d)*0.5f; l2lh.y = (a+b-c-d)*0.5f;
            l2hl.y = (a-b+c-d)*0.5f; l2hh.y = (a-b-c+d)*0.5f;
            const int o2 = u * 20 + 2 * g;
            *(float2*)(LL2 + o2) = l2ll; *(float2*)(LH2 + o2) = l2lh;
            *(float2*)(HL2 + o2) = l2hl; *(float2*)(HH2 + o2) = l2hh;
        }
    }
    __syncthreads();   // B1

    // ==== P2: conv7 (0-127) || conv5 (128-159) || DWT3 (160-189) ====
    if (tid < 128) {
        // conv7 on HH1, 32x16 in-tile outputs, 1x4 strip per thread.
        const int i = tid >> 3;
        const int j0 = (tid & 7) << 2;
        const float bias = b7[0];
        float a0 = bias, a1 = bias, a2 = bias, a3 = bias;
        #pragma unroll
        for (int dy = 0; dy < 7; ++dy) {
            const float* rp = HH1 + (i + dy + 1) * 44 + j0;
            float4 A = *(const float4*)(rp);
            float4 B = *(const float4*)(rp + 4);
            float4 C = *(const float4*)(rp + 8);
            const float* wr = w7 + dy * 7;
            float q0 = wr[0], q1 = wr[1], q2 = wr[2], q3 = wr[3], q4 = wr[4],
                  q5 = wr[5], q6 = wr[6];
            a0 += q0*A.y + q1*A.z + q2*A.w + q3*B.x + q4*B.y + q5*B.z + q6*B.w;
            a1 += q0*A.z + q1*A.w + q2*B.x + q3*B.y + q4*B.z + q5*B.w + q6*C.x;
            a2 += q0*A.w + q1*B.x + q2*B.y + q3*B.z + q4*B.w + q5*C.x + q6*C.y;
            a3 += q0*B.x + q1*B.y + q2*B.z + q3*B.w + q4*C.x + q5*C.y + q6*C.z;
        }
        *(float4*)(HH1C + i * 36 + j0) = make_float4(a0, a1, a2, a3);
    } else if (tid < 160) {
        // conv5 on HH2: 16x8 in-tile outputs, 1x4 strips (32 strips).
        const int s = tid - 128;
        const int i = s >> 2;
        const int j0 = (s & 3) << 2;
        const float bias = b5[0];
        float a0 = bias, a1 = bias, a2 = bias, a3 = bias;
        #pragma unroll
        for (int dy = 0; dy < 5; ++dy) {
            const float* rp = HH2 + (i + dy) * 20 + j0;
            float4 A = *(const float4*)(rp);
            float4 B = *(const float4*)(rp + 4);
            const float* wr = w5 + dy * 5;
            float q0 = wr[0], q1 = wr[1], q2 = wr[2], q3 = wr[3], q4 = wr[4];
            a0 += q0*A.x + q1*A.y + q2*A.z + q3*A.w + q4*B.x;
            a1 += q0*A.y + q1*A.z + q2*A.w + q3*B.x + q4*B.y;
            a2 += q0*A.z + q1*A.w + q2*B.x + q3*B.y + q4*B.z;
            a3 += q0*A.w + q1*B.x + q2*B.y + q3*B.z + q4*B.w;
        }
        *(float4*)(HH2C + i * 20 + j0) = make_float4(a0, a1, a2, a3);
    } else if (tid < 190) {
        // DWT3: LL2 (12x20 @20) -> level-3 10 wide x 6 tall @10. 30 items.
        const int t = tid - 160;
        const int u = t / 5, v2 = (t % 5) * 2;
        const float* rp = LL2 + (2 * u) * 20 + 2 * v2;
        float4 t0 = *(const float4*)(rp);
        float4 c0 = *(const float4*)(rp + 20);
        const int o = u * 10 + v2;
        *(float2*)(LL3 + o) = make_float2((t0.x + t0.y + c0.x + c0.y) * 0.5f,
                                          (t0.z + t0.w + c0.z + c0.w) * 0.5f);
        *(float2*)(LH3 + o) = make_float2((t0.x + t0.y - c0.x - c0.y) * 0.5f,
                                          (t0.z + t0.w - c0.z - c0.w) * 0.5f);
        *(float2*)(HL3 + o) = make_float2((t0.x - t0.y + c0.x - c0.y) * 0.5f,
                                          (t0.z - t0.w + c0.z - c0.w) * 0.5f);
        *(float2*)(HH3 + o) = make_float2((t0.x - t0.y - c0.x + c0.y) * 0.5f,
                                          (t0.z - t0.w - c0.z + c0.w) * 0.5f);
    }
    __syncthreads();   // B2

    // ==== P3: conv3 + IDWT3 + IDWT2 fused (tid 0-63) ====
    // Thread (p,c) produces LL2P[p][2c..2c+1] in registers, then the four
    // IDWT2 outputs they feed: rows 2p,2p+1 x col-pairs 2c,2c+1 -> LL1P.
    if (tid < 64) {
        const int p = tid >> 3, c = tid & 7;
        const int r = p >> 1;
        const float sr = (p & 1) ? -1.0f : 1.0f;
        float hh = b3[0];
        #pragma unroll
        for (int dy = 0; dy < 3; ++dy) {
            const float* row = HH3 + (r + dy) * 10 + c;
            const float* wr = w3 + dy * 3;
            hh += wr[0]*row[0] + wr[1]*row[1] + wr[2]*row[2];
        }
        const int li3 = (r + 1) * 10 + (c + 1);
        const float lo3 = LL3[li3] + sr * LH3[li3];
        const float hi3 = HL3[li3] + sr * hh;
        const float v0 = (lo3 + hi3) * 0.5f;   // LL2P[p][2c]
        const float v1 = (lo3 - hi3) * 0.5f;   // LL2P[p][2c+1]

        const int li2 = (p + 2) * 20 + (2 * c + 2);
        float2 lh2 = *(const float2*)(LH2 + li2);
        float2 hl2 = *(const float2*)(HL2 + li2);
        float2 hc  = *(const float2*)(HH2C + p * 20 + 2 * c);
        #pragma unroll
        for (int q = 0; q < 2; ++q) {
            const float s2 = q ? -1.0f : 1.0f;
            const float lo0 = v0 + s2 * lh2.x;
            const float hi0 = hl2.x + s2 * hc.x;
            const float lo1 = v1 + s2 * lh2.y;
            const float hi1 = hl2.y + s2 * hc.y;
            *(float4*)(LL1P + (2 * p + q) * 36 + 4 * c) =
                make_float4((lo0 + hi0) * 0.5f, (lo0 - hi0) * 0.5f,
                            (lo1 + hi1) * 0.5f, (lo1 - hi1) * 0.5f);
        }
    }
    __syncthreads();   // B3

    // ==== P4: IDWT1 -> out (64x32), NT float4 stores. 512 items / 2 rounds ====
    #pragma unroll
    for (int k = 0; k < 2; ++k) {
        const int idx = tid + 256 * k;
        const int p = idx >> 4;
        const int c2 = (idx & 15) * 2;
        const int r = p >> 1;
        const float sr = (p & 1) ? -1.0f : 1.0f;
        const int li = (r + 4) * 44 + (c2 + 4);
        const int ci = r * 36 + c2;
        float2 llp = *(const float2*)(LL1P + ci);
        float2 lh  = *(const float2*)(LH1 + li);
        float2 hl  = *(const float2*)(HL1 + li);
        float2 hhc = *(const float2*)(HH1C + ci);
        float lo0 = llp.x + sr * lh.x;
        float hi0 = hl.x + sr * hhc.x;
        float lo1 = llp.y + sr * lh.y;
        float hi1 = hl.y + sr * hhc.y;
        vf4 o = { (lo0 + hi0) * 0.5f, (lo0 - hi0) * 0.5f,
                  (lo1 + hi1) * 0.5f, (lo1 - hi1) * 0.5f };
        __builtin_nontemporal_store(
            o, (vf4*)(out + (size_t)(R0 + p) * IMG_N + C0 + 2 * c2));
    }
}

extern "C" void kernel_launch(void* const* d_in, const int* in_sizes, int n_in,
                              void* d_out, int out_size, void* d_ws, size_t ws_size,
                              hipStream_t stream) {
    (void)in_sizes; (void)n_in; (void)out_size; (void)d_ws; (void)ws_size;
    const float* x  = (const float*)d_in[0];
    const float* w3 = (const float*)d_in[1];
    const float* b3 = (const float*)d_in[2];
    const float* w5 = (const float*)d_in[3];
    const float* b5 = (const float*)d_in[4];
    const float* w7 = (const float*)d_in[5];
    const float* b7 = (const float*)d_in[6];
    float* out = (float*)d_out;

    dim3 grid(IMG_N / 64, IMG_N / 32);     // 64x128 tiles of 64x32 output px
    dim3 block(256);
    haar_fused<<<grid, block, 0, stream>>>(x, w3, b3, w5, b5, w7, b7, out);
}